// Round 7
// baseline (554.414 us; speedup 1.0000x reference)
//
#include <hip/hip_runtime.h>

#define N_NODES 8192
#define DIM 32
#define NCLS 16
#define SPLITK 8
#define KSEG (N_NODES / SPLITK) /* 1024 */
#define NCOLC 36                /* packed partial-C cols (36..47 structurally zero) */
#define NBLK 512
#define NTHR 256

typedef __bf16 bf16x8 __attribute__((ext_vector_type(8)));
typedef float f32x4 __attribute__((ext_vector_type(4)));

__device__ inline unsigned short f2bf(float f) {
  unsigned u = __float_as_uint(f);
  u = u + 0x7FFFu + ((u >> 16) & 1u);  // RNE
  return (unsigned short)(u >> 16);
}

__device__ inline float artanh_pos(float x) {  // x >= 0, clipped like jnp reference
  x = fminf(x, 1.0f - 1e-7f);
  return 0.5f * logf((1.0f + x) / (1.0f - x));
}

// ---- device-scope grid barrier: bar[0]=count, bar[1]=generation (memset 0 per call) ----
__device__ __forceinline__ void grid_sync(unsigned* bar) {
  __syncthreads();
  if (threadIdx.x == 0) {
    __threadfence();  // release: drain this block's stores past L2 (agent scope)
    unsigned g = atomicAdd(&bar[1], 0u);
    unsigned a = atomicAdd(&bar[0], 1u);
    if (a == NBLK - 1u) {
      atomicExch(&bar[0], 0u);
      __threadfence();
      atomicAdd(&bar[1], 1u);
    } else {
      while (atomicAdd(&bar[1], 0u) == g) __builtin_amdgcn_s_sleep(64);
    }
    __threadfence();  // acquire
  }
  __syncthreads();
}

// ---- pre: mobius_matvec + gamma -> G^T bf16 [48][N] ----
__device__ inline void pre_math(const float* __restrict__ Wl, const float x[DIM],
                                unsigned short* __restrict__ GT, int n) {
  float xn2 = 0.f;
#pragma unroll
  for (int i = 0; i < DIM; i++) xn2 += x[i] * x[i];
  float xn = sqrtf(fmaxf(xn2, 1e-30f));
  float mx[DIM];
#pragma unroll
  for (int j = 0; j < DIM; j++) mx[j] = 0.f;
  for (int i = 0; i < DIM; i++) {
    float xi = x[i];
#pragma unroll
    for (int j = 0; j < DIM; j++) mx[j] = fmaf(xi, Wl[i * DIM + j], mx[j]);
  }
  float mxn2 = 0.f;
#pragma unroll
  for (int j = 0; j < DIM; j++) mxn2 += mx[j] * mx[j];
  float mxn = sqrtf(fmaxf(mxn2, 1e-30f));
  float t = tanhf(mxn / xn * artanh_pos(xn));
  float sc = t / mxn;
  float xw[DIM];
  float x2n = 0.f;
#pragma unroll
  for (int j = 0; j < DIM; j++) { xw[j] = sc * mx[j]; x2n += xw[j] * xw[j]; }
  float gamma = 2.0f / fmaxf(1.0f - x2n, 1e-15f);
#pragma unroll
  for (int c = 0; c < DIM; c++) GT[(size_t)c * N_NODES + n] = f2bf(gamma * xw[c]);
  GT[(size_t)DIM * N_NODES + n] = f2bf(gamma - 1.0f);
  GT[(size_t)(DIM + 1) * N_NODES + n] = f2bf(1.0f);
#pragma unroll
  for (int c = DIM + 2; c < 48; c++) GT[(size_t)c * N_NODES + n] = 0;
}

// ---- post: splitK reduce + gyromidpoint + lincomb + sigma ----
__device__ inline void post_math(const float* __restrict__ Cpart, int n, float xo[DIM]) {
  float acc[NCOLC];
#pragma unroll
  for (int c = 0; c < NCOLC; c++) acc[c] = 0.f;
  for (int s = 0; s < SPLITK; s++) {
    const float4* p = (const float4*)(Cpart + ((size_t)s * N_NODES + n) * NCOLC);
#pragma unroll
    for (int q = 0; q < NCOLC / 4; q++) {
      float4 v = p[q];
      acc[q * 4 + 0] += v.x; acc[q * 4 + 1] += v.y;
      acc[q * 4 + 2] += v.z; acc[q * 4 + 3] += v.w;
    }
  }
  float denom = acc[32];
  float alpha = acc[33];
  denom = (denom >= 0.f) ? fmaxf(denom, 1e-10f) : fminf(denom, -1e-10f);
  float inv = 1.0f / denom;
  float v[DIM];
  float vn2 = 0.f;
#pragma unroll
  for (int c = 0; c < DIM; c++) { v[c] = acc[c] * inv; vn2 += v[c] * v[c]; }
  float vn = sqrtf(fmaxf(vn2, 1e-30f));
  float un = alpha * 0.5f * artanh_pos(vn);
  float su = un / vn;
  float r[DIM];
  float rn2 = 0.f;
#pragma unroll
  for (int c = 0; c < DIM; c++) { r[c] = fmaxf(su * v[c], 0.f); rn2 += r[c] * r[c]; }
  float rn = sqrtf(fmaxf(rn2, 1e-30f));
  float so = tanhf(rn) / rn;
#pragma unroll
  for (int c = 0; c < DIM; c++) xo[c] = so * r[c];
}

// ---- MFMA pass: Cpart[by] += A[128 rows, KSEG] @ BT^T ----
template <int NF>
__device__ __forceinline__ void mm_pass(const unsigned short* __restrict__ A,
                                        const unsigned short* __restrict__ BT,
                                        float* __restrict__ Cpart) {
  const int lane = threadIdx.x & 63;
  const int wid = threadIdx.x >> 6;
  const int bx = blockIdx.x & 63;
  const int by = blockIdx.x >> 6;
  const int r0 = bx * 128 + wid * 32;
  const int k0 = by * KSEG;
  const int lr = lane & 15;
  const int lk = (lane >> 4) * 8;
  f32x4 acc[2][NF];
#pragma unroll
  for (int m = 0; m < 2; m++)
#pragma unroll
    for (int nf = 0; nf < NF; nf++) acc[m][nf] = (f32x4){0.f, 0.f, 0.f, 0.f};
  const unsigned short* pa0 = A + (size_t)(r0 + lr) * N_NODES + k0 + lk;
  const unsigned short* pa1 = pa0 + (size_t)16 * N_NODES;
  const unsigned short* pb[NF];
#pragma unroll
  for (int nf = 0; nf < NF; nf++) pb[nf] = BT + (size_t)(nf * 16 + lr) * N_NODES + k0 + lk;
#pragma unroll 4
  for (int kk = 0; kk < KSEG; kk += 32) {
    bf16x8 a0 = *(const bf16x8*)(pa0 + kk);
    bf16x8 a1 = *(const bf16x8*)(pa1 + kk);
#pragma unroll
    for (int nf = 0; nf < NF; nf++) {
      bf16x8 b = *(const bf16x8*)(pb[nf] + kk);
      acc[0][nf] = __builtin_amdgcn_mfma_f32_16x16x32_bf16(a0, b, acc[0][nf], 0, 0, 0);
      acc[1][nf] = __builtin_amdgcn_mfma_f32_16x16x32_bf16(a1, b, acc[1][nf], 0, 0, 0);
    }
  }
  const int NCOL = (NF == 3) ? NCOLC : NF * 16;
  float* Cb = Cpart + (size_t)by * N_NODES * NCOL;
#pragma unroll
  for (int m = 0; m < 2; m++)
#pragma unroll
    for (int nf = 0; nf < NF; nf++) {
      if (NF == 3 && nf == 2 && lr >= 4) continue;  // zero cols never read
#pragma unroll
      for (int j = 0; j < 4; j++) {
        int row = r0 + m * 16 + (lane >> 4) * 4 + j;
        int col = nf * 16 + lr;
        Cb[(size_t)row * NCOL + col] = acc[m][nf][j];
      }
    }
}

// ---- the whole network in one persistent kernel ----
__global__ __launch_bounds__(NTHR, 2) void k_fused(
    const float* __restrict__ X, const float* __restrict__ A,
    const float* __restrict__ W1, const float* __restrict__ W2,
    const float* __restrict__ WL, const float* __restrict__ PK,
    float* __restrict__ out, unsigned short* __restrict__ Abf,
    unsigned short* __restrict__ GT, float* __restrict__ Cpart,
    unsigned short* __restrict__ LT, unsigned* __restrict__ bar) {
  __shared__ float sW[DIM * DIM];
  __shared__ float sB[NCLS * DIM];
  __shared__ float s_an[NCLS], s_lam[NCLS], s_b2[NCLS];
  const int tid = threadIdx.x;

  // ======== P1: pre1 (16 lanes/block) + streaming convert A->bf16 ========
  for (int i = tid; i < DIM * DIM; i += NTHR) sW[i] = W1[i];
  __syncthreads();
  if (tid < 16) {
    const int n = blockIdx.x * 16 + tid;
    float x[DIM];
#pragma unroll
    for (int i = 0; i < DIM; i += 4) {
      float4 v = *(const float4*)(X + (size_t)n * DIM + i);
      x[i] = v.x; x[i + 1] = v.y; x[i + 2] = v.z; x[i + 3] = v.w;
    }
    pre_math(sW, x, GT, n);
  }
  {
    const size_t total = (size_t)N_NODES * N_NODES;
    const size_t nlanes = (size_t)NBLK * NTHR;
    const size_t t = (size_t)blockIdx.x * NTHR + tid;
    for (size_t base = 0; base < total; base += 8 * nlanes) {
      size_t i0 = base + 4 * t;
      size_t i1 = base + 4 * nlanes + 4 * t;
      float4 v0 = *(const float4*)(A + i0);
      float4 v1 = *(const float4*)(A + i1);
      uint2 o0, o1;
      o0.x = f2bf(v0.x) | ((unsigned)f2bf(v0.y) << 16);
      o0.y = f2bf(v0.z) | ((unsigned)f2bf(v0.w) << 16);
      o1.x = f2bf(v1.x) | ((unsigned)f2bf(v1.y) << 16);
      o1.y = f2bf(v1.z) | ((unsigned)f2bf(v1.w) << 16);
      *(uint2*)(Abf + i0) = o0;
      *(uint2*)(Abf + i1) = o1;
    }
  }
  grid_sync(bar);

  // ======== P2: mm1 ========
  mm_pass<3>(Abf, GT, Cpart);
  grid_sync(bar);

  // ======== P3: post(layer1) + pre(layer2), 16 lanes/block ========
  for (int i = tid; i < DIM * DIM; i += NTHR) sW[i] = W2[i];
  __syncthreads();
  if (tid < 16) {
    const int n = blockIdx.x * 16 + tid;
    float x[DIM];
    post_math(Cpart, n, x);
    pre_math(sW, x, GT, n);
  }
  grid_sync(bar);

  // ======== P4: mm2 ========
  mm_pass<3>(Abf, GT, Cpart);
  grid_sync(bar);

  // ======== P5: post(layer2) + MLR logits -> LT bf16 [16][N] ========
  for (int i = tid; i < DIM * NCLS; i += NTHR) { sW[i] = WL[i]; sB[i] = PK[i]; }
  __syncthreads();
  if (tid < NCLS) {
    const int c = tid;
    float b2 = 0.f, w2 = 0.f;
    for (int d = 0; d < DIM; d++) {
      b2 += sB[c * DIM + d] * sB[c * DIM + d];
      w2 += sW[d * NCLS + c] * sW[d * NCLS + c];
    }
    s_b2[c] = b2;
    s_an[c] = fmaxf(sqrtf(w2), 1e-10f);
    s_lam[c] = 2.0f / fmaxf(1.0f - b2, 1e-15f);
  }
  __syncthreads();
  if (tid < 16) {
    const int n = blockIdx.x * 16 + tid;
    float x[DIM];
    post_math(Cpart, n, x);
    float y2 = 0.f;
#pragma unroll
    for (int i = 0; i < DIM; i++) y2 += x[i] * x[i];
    for (int c = 0; c < NCLS; c++) {
      float b2 = s_b2[c];
      float bx = 0.f;
      for (int d = 0; d < DIM; d++) bx += sB[c * DIM + d] * x[d];
      float xy = -bx;
      float f1 = 1.0f + 2.0f * xy + y2;
      float f2 = 1.0f - b2;
      float den = fmaxf(1.0f + 2.0f * xy + b2 * y2, 1e-15f);
      float invden = 1.0f / den;
      float zn2 = 0.f, za = 0.f;
      for (int d = 0; d < DIM; d++) {
        float z = (f1 * (-sB[c * DIM + d]) + f2 * x[d]) * invden;
        zn2 += z * z;
        za += z * sW[d * NCLS + c];
      }
      float zn = fmaxf(sqrtf(fmaxf(zn2, 1e-30f)), 1e-10f);
      float dist = asinhf(2.0f * za / ((1.0f - zn * zn) * s_an[c]));
      LT[(size_t)c * N_NODES + n] = f2bf(s_lam[c] * s_an[c] * dist);
    }
  }
  grid_sync(bar);

  // ======== P6: mm3 (logit aggregation) ========
  mm_pass<1>(Abf, LT, Cpart);
  grid_sync(bar);

  // ======== P7: final splitK reduce (one element per lane) ========
  {
    const int i = blockIdx.x * NTHR + tid;  // NBLK*NTHR == N_NODES*NCLS
    float s = 0.f;
#pragma unroll
    for (int q = 0; q < SPLITK; q++) s += Cpart[(size_t)q * (N_NODES * NCLS) + i];
    out[i] = s;
  }
}

extern "C" void kernel_launch(void* const* d_in, const int* in_sizes, int n_in,
                              void* d_out, int out_size, void* d_ws, size_t ws_size,
                              hipStream_t stream) {
  (void)in_sizes; (void)n_in; (void)out_size; (void)ws_size;
  const float* X  = (const float*)d_in[0];
  const float* A  = (const float*)d_in[1];
  const float* W1 = (const float*)d_in[2];
  const float* W2 = (const float*)d_in[3];
  const float* WL = (const float*)d_in[4];
  const float* PK = (const float*)d_in[5];
  float* out = (float*)d_out;

  char* ws = (char*)d_ws;
  unsigned short* Abf = (unsigned short*)ws;                  // 134,217,728 B
  unsigned short* GT  = (unsigned short*)(ws + 134217728);    //     786,432 B
  float* Cpart        = (float*)(ws + 135004160);             //   9,437,184 B
  unsigned short* LT  = (unsigned short*)(ws + 144441344);    //     262,144 B
  unsigned* bar       = (unsigned*)(ws + 144703488);          //          64 B

  hipMemsetAsync(ws + 144703488, 0, 64, stream);  // barrier state must start at 0
  k_fused<<<NBLK, NTHR, 0, stream>>>(X, A, W1, W2, WL, PK, out, Abf, GT, Cpart, LT, bar);
}

// Round 8
// 225.760 us; speedup vs baseline: 2.4558x; 2.4558x over previous
//
#include <hip/hip_runtime.h>

#define N_NODES 8192
#define DIM 32
#define NCLS 16
#define SPLITK 16
#define KSEG (N_NODES / SPLITK) /* 512 */
#define NCOLC 36                /* packed partial-C columns (cols 36..47 structurally zero) */
#define NKT (N_NODES / 32)      /* 256 k-tiles per row stripe */
#define RT_STRIDE ((size_t)NKT * 512) /* elems per row-tile stripe */

typedef __bf16 bf16x8 __attribute__((ext_vector_type(8)));
typedef float f32x4 __attribute__((ext_vector_type(4)));

__device__ inline unsigned short f2bf(float f) {
  unsigned u = __float_as_uint(f);
  u = u + 0x7FFFu + ((u >> 16) & 1u);  // RNE
  return (unsigned short)(u >> 16);
}

__device__ inline float artanh_pos(float x) {  // x >= 0, clipped like jnp reference
  x = fminf(x, 1.0f - 1e-7f);
  return 0.5f * logf((1.0f + x) / (1.0f - x));
}

__device__ inline bf16x8 cvt8(float4 lo, float4 hi) {
  bf16x8 r;
  r[0] = (__bf16)lo.x; r[1] = (__bf16)lo.y; r[2] = (__bf16)lo.z; r[3] = (__bf16)lo.w;
  r[4] = (__bf16)hi.x; r[5] = (__bf16)hi.y; r[6] = (__bf16)hi.z; r[7] = (__bf16)hi.w;
  return r;
}

// ---- fragment-linear tile indexing ----
// A: [rt][kt][16 rows][32 k]  (1KB tiles; frag load = dense wave load)
__device__ inline size_t a_tile_idx(int r, int k) {
  return ((size_t)(r >> 4) * NKT + (k >> 5)) * 512 + (size_t)((r & 15) * 32 + (k & 31));
}
// G: [nt][3 colblk][16 col][32 n]
__device__ inline size_t g_tile_idx(int c, int n) {
  return ((size_t)(n >> 5) * 3 + (c >> 4)) * 512 + (size_t)((c & 15) * 32 + (n & 31));
}
// L: [nt][16 col][32 n]
__device__ inline size_t l_tile_idx(int c, int n) {
  return (size_t)(n >> 5) * 512 + (size_t)(c * 32 + (n & 31));
}

// ---------------- A fp32 -> bf16 (RNE) into fragment-linear tiles ----------------
// Reads stay lane-dense row-major streams; writes are 16B/lane into tiles.
__global__ __launch_bounds__(256) void k_convert(const float* __restrict__ A,
                                                 unsigned short* __restrict__ Abf) {
  const size_t total = (size_t)N_NODES * N_NODES;
  const size_t nl = (size_t)gridDim.x * blockDim.x;
  const size_t t = (size_t)blockIdx.x * blockDim.x + threadIdx.x;
  for (size_t base = 0; base < total; base += 8 * nl) {
    size_t i = base + 8 * t;  // 8 consecutive elems of one row (8-aligned => one k-tile)
    float4 v0 = *(const float4*)(A + i);
    float4 v1 = *(const float4*)(A + i + 4);
    bf16x8 o = cvt8(v0, v1);
    int r = (int)(i >> 13);
    int k = (int)(i & 8191);
    *(bf16x8*)(Abf + a_tile_idx(r, k)) = o;
  }
}

// ---------------- pre: mobius_matvec + gamma -> G tiles ----------------
__device__ inline void pre_math(const float* __restrict__ Wl, const float x[DIM],
                                unsigned short* __restrict__ GT, int n) {
  float xn2 = 0.f;
#pragma unroll
  for (int i = 0; i < DIM; i++) xn2 += x[i] * x[i];
  float xn = sqrtf(fmaxf(xn2, 1e-30f));
  float mx[DIM];
#pragma unroll
  for (int j = 0; j < DIM; j++) mx[j] = 0.f;
  for (int i = 0; i < DIM; i++) {
    float xi = x[i];
#pragma unroll
    for (int j = 0; j < DIM; j++) mx[j] = fmaf(xi, Wl[i * DIM + j], mx[j]);
  }
  float mxn2 = 0.f;
#pragma unroll
  for (int j = 0; j < DIM; j++) mxn2 += mx[j] * mx[j];
  float mxn = sqrtf(fmaxf(mxn2, 1e-30f));
  float t = tanhf(mxn / xn * artanh_pos(xn));
  float sc = t / mxn;
  float xw[DIM];
  float x2n = 0.f;
#pragma unroll
  for (int j = 0; j < DIM; j++) { xw[j] = sc * mx[j]; x2n += xw[j] * xw[j]; }
  float gamma = 2.0f / fmaxf(1.0f - x2n, 1e-15f);
#pragma unroll
  for (int c = 0; c < DIM; c++) GT[g_tile_idx(c, n)] = f2bf(gamma * xw[c]);
  GT[g_tile_idx(32, n)] = f2bf(gamma - 1.0f);
  GT[g_tile_idx(33, n)] = f2bf(1.0f);
#pragma unroll
  for (int c = DIM + 2; c < 48; c++) GT[g_tile_idx(c, n)] = 0;
}

__global__ void k_pre1(const float* __restrict__ X, const float* __restrict__ W,
                       unsigned short* __restrict__ GT) {
  __shared__ float Wl[DIM * DIM];
  for (int i = threadIdx.x; i < DIM * DIM; i += blockDim.x) Wl[i] = W[i];
  __syncthreads();
  const int n = blockIdx.x * blockDim.x + threadIdx.x;
  float x[DIM];
#pragma unroll
  for (int i = 0; i < DIM; i += 4) {
    float4 v = *(const float4*)(X + (size_t)n * DIM + i);
    x[i] = v.x; x[i + 1] = v.y; x[i + 2] = v.z; x[i + 3] = v.w;
  }
  pre_math(Wl, x, GT, n);
}

// ---------------- post math: reads reduced C [N][36] ----------------
__device__ inline void post_math(const float* __restrict__ Cred, int n, float xo[DIM]) {
  float acc[36];
  const float4* p = (const float4*)(Cred + (size_t)n * NCOLC);
#pragma unroll
  for (int q = 0; q < 9; q++) {
    float4 v = p[q];
    acc[q * 4 + 0] = v.x; acc[q * 4 + 1] = v.y;
    acc[q * 4 + 2] = v.z; acc[q * 4 + 3] = v.w;
  }
  float denom = acc[32];
  float alpha = acc[33];
  denom = (denom >= 0.f) ? fmaxf(denom, 1e-10f) : fminf(denom, -1e-10f);
  float inv = 1.0f / denom;
  float v[DIM];
  float vn2 = 0.f;
#pragma unroll
  for (int c = 0; c < DIM; c++) { v[c] = acc[c] * inv; vn2 += v[c] * v[c]; }
  float vn = sqrtf(fmaxf(vn2, 1e-30f));
  float un = alpha * 0.5f * artanh_pos(vn);
  float su = un / vn;
  float r[DIM];
  float rn2 = 0.f;
#pragma unroll
  for (int c = 0; c < DIM; c++) { r[c] = fmaxf(su * v[c], 0.f); rn2 += r[c] * r[c]; }
  float rn = sqrtf(fmaxf(rn2, 1e-30f));
  float so = tanhf(rn) / rn;
#pragma unroll
  for (int c = 0; c < DIM; c++) xo[c] = so * r[c];
}

__global__ void k_postpre(const float* __restrict__ Cred, const float* __restrict__ W,
                          unsigned short* __restrict__ GT) {
  __shared__ float Wl[DIM * DIM];
  for (int i = threadIdx.x; i < DIM * DIM; i += blockDim.x) Wl[i] = W[i];
  __syncthreads();
  const int n = blockIdx.x * blockDim.x + threadIdx.x;
  float x[DIM];
  post_math(Cred, n, x);
  pre_math(Wl, x, GT, n);
}

__global__ void k_postlogits(const float* __restrict__ Cred, const float* __restrict__ Wl_g,
                             const float* __restrict__ B_g, unsigned short* __restrict__ LT) {
  __shared__ float Wc[DIM * NCLS];
  __shared__ float Bc[NCLS * DIM];
  __shared__ float an_s[NCLS], lam_s[NCLS], b2_s[NCLS];
  for (int i = threadIdx.x; i < DIM * NCLS; i += blockDim.x) { Wc[i] = Wl_g[i]; Bc[i] = B_g[i]; }
  __syncthreads();
  if (threadIdx.x < NCLS) {
    int c = threadIdx.x;
    float b2 = 0.f, w2 = 0.f;
    for (int d = 0; d < DIM; d++) {
      b2 += Bc[c * DIM + d] * Bc[c * DIM + d];
      w2 += Wc[d * NCLS + c] * Wc[d * NCLS + c];
    }
    b2_s[c] = b2;
    an_s[c] = fmaxf(sqrtf(w2), 1e-10f);
    lam_s[c] = 2.0f / fmaxf(1.0f - b2, 1e-15f);
  }
  __syncthreads();
  const int n = blockIdx.x * blockDim.x + threadIdx.x;
  float x[DIM];
  post_math(Cred, n, x);
  float y2 = 0.f;
#pragma unroll
  for (int i = 0; i < DIM; i++) y2 += x[i] * x[i];
  for (int c = 0; c < NCLS; c++) {
    float b2 = b2_s[c];
    float bx = 0.f;
    for (int d = 0; d < DIM; d++) bx += Bc[c * DIM + d] * x[d];
    float xy = -bx;
    float f1 = 1.0f + 2.0f * xy + y2;
    float f2 = 1.0f - b2;
    float den = fmaxf(1.0f + 2.0f * xy + b2 * y2, 1e-15f);
    float invden = 1.0f / den;
    float zn2 = 0.f, za = 0.f;
    for (int d = 0; d < DIM; d++) {
      float z = (f1 * (-Bc[c * DIM + d]) + f2 * x[d]) * invden;
      zn2 += z * z;
      za += z * Wc[d * NCLS + c];
    }
    float zn = fmaxf(sqrtf(fmaxf(zn2, 1e-30f)), 1e-10f);
    float dist = asinhf(2.0f * za / ((1.0f - zn * zn) * an_s[c]));
    LT[l_tile_idx(c, n)] = f2bf(lam_s[c] * an_s[c] * dist);
  }
}

// ---------------- MFMA matmul over fragment-linear tiles ----------------
// Every A-frag and B-frag load is ONE dense 1KB wave load (zero scatter).
template <int NF>
__global__ __launch_bounds__(256) void k_mm(const unsigned short* __restrict__ A,
                                            const unsigned short* __restrict__ BT,
                                            float* __restrict__ Cpart) {
  const int lane = threadIdx.x & 63;
  const int wid = threadIdx.x >> 6;
  const int r0 = blockIdx.x * 128 + wid * 32;
  const int kt0 = blockIdx.y * (KSEG / 32);  // global k-tile base
  const int lr = lane & 15;
  const int lkg = lane >> 4;
  const int poff = lr * 32 + lkg * 8;  // per-lane elem offset inside a tile
  const int BS = (NF == 3) ? 3 : 1;    // B tiles per k-tile
  f32x4 acc[2][NF];
#pragma unroll
  for (int m = 0; m < 2; m++)
#pragma unroll
    for (int nf = 0; nf < NF; nf++) acc[m][nf] = (f32x4){0.f, 0.f, 0.f, 0.f};
  const unsigned short* pa0 = A + ((size_t)(r0 >> 4) * NKT + kt0) * 512 + poff;
  const unsigned short* pa1 = pa0 + RT_STRIDE;
  const unsigned short* pbB = BT + (size_t)kt0 * BS * 512 + poff;
#pragma unroll 4
  for (int kt = 0; kt < KSEG / 32; kt++) {
    bf16x8 a0 = *(const bf16x8*)(pa0 + (size_t)kt * 512);
    bf16x8 a1 = *(const bf16x8*)(pa1 + (size_t)kt * 512);
#pragma unroll
    for (int nf = 0; nf < NF; nf++) {
      bf16x8 b = *(const bf16x8*)(pbB + (size_t)(kt * BS + nf) * 512);
      acc[0][nf] = __builtin_amdgcn_mfma_f32_16x16x32_bf16(a0, b, acc[0][nf], 0, 0, 0);
      acc[1][nf] = __builtin_amdgcn_mfma_f32_16x16x32_bf16(a1, b, acc[1][nf], 0, 0, 0);
    }
  }
  const int NCOL = (NF == 3) ? NCOLC : NF * 16;
  float* Cb = Cpart + (size_t)blockIdx.y * N_NODES * NCOL;
#pragma unroll
  for (int m = 0; m < 2; m++)
#pragma unroll
    for (int nf = 0; nf < NF; nf++) {
      if (NF == 3 && nf == 2 && lr >= 4) continue;  // cols 36..47 never read
#pragma unroll
      for (int j = 0; j < 4; j++) {
        int row = r0 + m * 16 + lkg * 4 + j;
        int col = nf * 16 + lr;
        Cb[(size_t)row * NCOL + col] = acc[m][nf][j];
      }
    }
}

// ---------------- splitK reduce (contiguous) ----------------
template <int TOTAL>
__global__ void k_red(const float* __restrict__ part, float* __restrict__ outb) {
  int i = blockIdx.x * blockDim.x + threadIdx.x;
  if (i < TOTAL) {
    float s = 0.f;
#pragma unroll
    for (int q = 0; q < SPLITK; q++) s += part[(size_t)q * TOTAL + i];
    outb[i] = s;
  }
}

extern "C" void kernel_launch(void* const* d_in, const int* in_sizes, int n_in,
                              void* d_out, int out_size, void* d_ws, size_t ws_size,
                              hipStream_t stream) {
  (void)in_sizes; (void)n_in; (void)out_size; (void)ws_size;
  const float* X  = (const float*)d_in[0];
  const float* A  = (const float*)d_in[1];
  const float* W1 = (const float*)d_in[2];
  const float* W2 = (const float*)d_in[3];
  const float* WL = (const float*)d_in[4];
  const float* PK = (const float*)d_in[5];
  float* out = (float*)d_out;

  char* ws = (char*)d_ws;
  unsigned short* Abf = (unsigned short*)ws;                  // 134,217,728 B (tiled)
  unsigned short* GT  = (unsigned short*)(ws + 134217728);    //     786,432 B (tiled)
  float* Cpart        = (float*)(ws + 135004160);             //  18,874,368 B
  float* Cred         = (float*)(ws + 153878528);             //   1,179,648 B
  unsigned short* LT  = (unsigned short*)(ws + 155058176);    //     262,144 B (tiled)

  // streaming convert: the ONLY kernel that touches HBM-cold A
  k_convert<<<2048, 256, 0, stream>>>(A, Abf);

  // layer 1
  k_pre1<<<N_NODES / 64, 64, 0, stream>>>(X, W1, GT);
  k_mm<3><<<dim3(64, SPLITK), 256, 0, stream>>>(Abf, GT, Cpart);
  k_red<N_NODES * NCOLC><<<N_NODES * NCOLC / 256, 256, 0, stream>>>(Cpart, Cred);
  k_postpre<<<N_NODES / 64, 64, 0, stream>>>(Cred, W2, GT);

  // layer 2
  k_mm<3><<<dim3(64, SPLITK), 256, 0, stream>>>(Abf, GT, Cpart);
  k_red<N_NODES * NCOLC><<<N_NODES * NCOLC / 256, 256, 0, stream>>>(Cpart, Cred);
  k_postlogits<<<N_NODES / 64, 64, 0, stream>>>(Cred, WL, PK, LT);

  // logits aggregation
  k_mm<1><<<dim3(64, SPLITK), 256, 0, stream>>>(Abf, LT, Cpart);
  k_red<N_NODES * NCLS><<<N_NODES * NCLS / 256, 256, 0, stream>>>(Cpart, out);
}

// Round 9
// 212.618 us; speedup vs baseline: 2.6076x; 1.0618x over previous
//
#include <hip/hip_runtime.h>

#define N_NODES 8192
#define DIM 32
#define NCLS 16
#define SPLITK 16
#define KSEG (N_NODES / SPLITK) /* 512 */
#define NCOLC 36                /* packed partial-C columns (cols 36..47 structurally zero) */
#define NKT (N_NODES / 32)      /* 256 k-tiles per row stripe */
#define RT_STRIDE ((size_t)NKT * 512) /* elems per row-tile stripe */
#define PITCH 520               /* LDS row pitch in bf16 elems (1040B, 16B-aligned) */

typedef __bf16 bf16x8 __attribute__((ext_vector_type(8)));
typedef float f32x4 __attribute__((ext_vector_type(4)));

__device__ inline unsigned short f2bf(float f) {
  unsigned u = __float_as_uint(f);
  u = u + 0x7FFFu + ((u >> 16) & 1u);  // RNE
  return (unsigned short)(u >> 16);
}

__device__ inline float artanh_pos(float x) {  // x >= 0, clipped like jnp reference
  x = fminf(x, 1.0f - 1e-7f);
  return 0.5f * logf((1.0f + x) / (1.0f - x));
}

// ---- fragment-linear tile indexing ----
// A: [rt][kt][16 rows][32 k]  (1KB tiles; frag load = dense wave load)
__device__ inline size_t a_tile_idx(int r, int k) {
  return ((size_t)(r >> 4) * NKT + (k >> 5)) * 512 + (size_t)((r & 15) * 32 + (k & 31));
}
// G: [nt][3 colblk][16 col][32 n]
__device__ inline size_t g_tile_idx(int c, int n) {
  return ((size_t)(n >> 5) * 3 + (c >> 4)) * 512 + (size_t)((c & 15) * 32 + (n & 31));
}
// L: [nt][16 col][32 n]
__device__ inline size_t l_tile_idx(int c, int n) {
  return (size_t)(n >> 5) * 512 + (size_t)(c * 32 + (n & 31));
}

// ---------------- A fp32 -> bf16 into fragment-linear tiles, LDS-transposed ----------------
// Supertile = 16 rows x 512 k  (fp32 32KB in, bf16 16KB out; out is 16KB CONTIGUOUS).
// Phase 1: dense 1KB-per-instruction global reads -> convert -> contiguous LDS writes.
// Phase 2: fragment-ordered LDS reads (<=2-way alias) -> dense 1KB-per-instruction stores.
__global__ __launch_bounds__(256) void k_convert(const float* __restrict__ A,
                                                 unsigned short* __restrict__ Abf) {
  __shared__ unsigned short lds[16 * PITCH];  // 16,640 B
  const int t = threadIdx.x;
  const int NST = (N_NODES / 16) * (N_NODES / 512);  // 8192 supertiles
  for (int st = blockIdx.x; st < NST; st += gridDim.x) {
    const int rt = st >> 4;  // row-tile index (16 rows)
    const int ks = st & 15;  // k-supertile (512 k)
    const float* src = A + (size_t)(rt * 16) * N_NODES + ks * 512;
    // phase 1: read + convert + LDS stage (2 rows per volley, wave-dense reads)
#pragma unroll
    for (int v = 0; v < 8; v++) {
      const int row = 2 * v + (t >> 7);
      const int k = (t & 127) * 4;
      float4 f = *(const float4*)(src + (size_t)row * N_NODES + k);
      uint2 o;
      o.x = f2bf(f.x) | ((unsigned)f2bf(f.y) << 16);
      o.y = f2bf(f.z) | ((unsigned)f2bf(f.w) << 16);
      *(uint2*)(lds + row * PITCH + k) = o;
    }
    __syncthreads();
    // phase 2: fragment-ordered LDS read -> dense contiguous global store
    unsigned short* dst = Abf + (size_t)st * 8192;
#pragma unroll
    for (int u = 0; u < 4; u++) {
      const int p = u * 256 + t;       // 16B-chunk index within 16KB supertile
      const int kt = p >> 6;           // local tile 0..15
      const int q = p & 63;            // chunk within tile
      const int row = q >> 2;          // tile row 0..15
      const int kl = (q & 3) * 8;      // k offset within tile row
      bf16x8 val = *(const bf16x8*)(lds + row * PITCH + kt * 32 + kl);
      *(bf16x8*)(dst + (size_t)p * 8) = val;
    }
    __syncthreads();
  }
}

// ---------------- pre: mobius_matvec + gamma -> G tiles ----------------
__device__ inline void pre_math(const float* __restrict__ Wl, const float x[DIM],
                                unsigned short* __restrict__ GT, int n) {
  float xn2 = 0.f;
#pragma unroll
  for (int i = 0; i < DIM; i++) xn2 += x[i] * x[i];
  float xn = sqrtf(fmaxf(xn2, 1e-30f));
  float mx[DIM];
#pragma unroll
  for (int j = 0; j < DIM; j++) mx[j] = 0.f;
  for (int i = 0; i < DIM; i++) {
    float xi = x[i];
#pragma unroll
    for (int j = 0; j < DIM; j++) mx[j] = fmaf(xi, Wl[i * DIM + j], mx[j]);
  }
  float mxn2 = 0.f;
#pragma unroll
  for (int j = 0; j < DIM; j++) mxn2 += mx[j] * mx[j];
  float mxn = sqrtf(fmaxf(mxn2, 1e-30f));
  float t = tanhf(mxn / xn * artanh_pos(xn));
  float sc = t / mxn;
  float xw[DIM];
  float x2n = 0.f;
#pragma unroll
  for (int j = 0; j < DIM; j++) { xw[j] = sc * mx[j]; x2n += xw[j] * xw[j]; }
  float gamma = 2.0f / fmaxf(1.0f - x2n, 1e-15f);
#pragma unroll
  for (int c = 0; c < DIM; c++) GT[g_tile_idx(c, n)] = f2bf(gamma * xw[c]);
  GT[g_tile_idx(32, n)] = f2bf(gamma - 1.0f);
  GT[g_tile_idx(33, n)] = f2bf(1.0f);
#pragma unroll
  for (int c = DIM + 2; c < 48; c++) GT[g_tile_idx(c, n)] = 0;
}

__global__ void k_pre1(const float* __restrict__ X, const float* __restrict__ W,
                       unsigned short* __restrict__ GT) {
  __shared__ float Wl[DIM * DIM];
  for (int i = threadIdx.x; i < DIM * DIM; i += blockDim.x) Wl[i] = W[i];
  __syncthreads();
  const int n = blockIdx.x * blockDim.x + threadIdx.x;
  float x[DIM];
#pragma unroll
  for (int i = 0; i < DIM; i += 4) {
    float4 v = *(const float4*)(X + (size_t)n * DIM + i);
    x[i] = v.x; x[i + 1] = v.y; x[i + 2] = v.z; x[i + 3] = v.w;
  }
  pre_math(Wl, x, GT, n);
}

// ---------------- post math: reads reduced C [N][36] ----------------
__device__ inline void post_math(const float* __restrict__ Cred, int n, float xo[DIM]) {
  float acc[36];
  const float4* p = (const float4*)(Cred + (size_t)n * NCOLC);
#pragma unroll
  for (int q = 0; q < 9; q++) {
    float4 v = p[q];
    acc[q * 4 + 0] = v.x; acc[q * 4 + 1] = v.y;
    acc[q * 4 + 2] = v.z; acc[q * 4 + 3] = v.w;
  }
  float denom = acc[32];
  float alpha = acc[33];
  denom = (denom >= 0.f) ? fmaxf(denom, 1e-10f) : fminf(denom, -1e-10f);
  float inv = 1.0f / denom;
  float v[DIM];
  float vn2 = 0.f;
#pragma unroll
  for (int c = 0; c < DIM; c++) { v[c] = acc[c] * inv; vn2 += v[c] * v[c]; }
  float vn = sqrtf(fmaxf(vn2, 1e-30f));
  float un = alpha * 0.5f * artanh_pos(vn);
  float su = un / vn;
  float r[DIM];
  float rn2 = 0.f;
#pragma unroll
  for (int c = 0; c < DIM; c++) { r[c] = fmaxf(su * v[c], 0.f); rn2 += r[c] * r[c]; }
  float rn = sqrtf(fmaxf(rn2, 1e-30f));
  float so = tanhf(rn) / rn;
#pragma unroll
  for (int c = 0; c < DIM; c++) xo[c] = so * r[c];
}

__global__ void k_postpre(const float* __restrict__ Cred, const float* __restrict__ W,
                          unsigned short* __restrict__ GT) {
  __shared__ float Wl[DIM * DIM];
  for (int i = threadIdx.x; i < DIM * DIM; i += blockDim.x) Wl[i] = W[i];
  __syncthreads();
  const int n = blockIdx.x * blockDim.x + threadIdx.x;
  float x[DIM];
  post_math(Cred, n, x);
  pre_math(Wl, x, GT, n);
}

__global__ void k_postlogits(const float* __restrict__ Cred, const float* __restrict__ Wl_g,
                             const float* __restrict__ B_g, unsigned short* __restrict__ LT) {
  __shared__ float Wc[DIM * NCLS];
  __shared__ float Bc[NCLS * DIM];
  __shared__ float an_s[NCLS], lam_s[NCLS], b2_s[NCLS];
  for (int i = threadIdx.x; i < DIM * NCLS; i += blockDim.x) { Wc[i] = Wl_g[i]; Bc[i] = B_g[i]; }
  __syncthreads();
  if (threadIdx.x < NCLS) {
    int c = threadIdx.x;
    float b2 = 0.f, w2 = 0.f;
    for (int d = 0; d < DIM; d++) {
      b2 += Bc[c * DIM + d] * Bc[c * DIM + d];
      w2 += Wc[d * NCLS + c] * Wc[d * NCLS + c];
    }
    b2_s[c] = b2;
    an_s[c] = fmaxf(sqrtf(w2), 1e-10f);
    lam_s[c] = 2.0f / fmaxf(1.0f - b2, 1e-15f);
  }
  __syncthreads();
  const int n = blockIdx.x * blockDim.x + threadIdx.x;
  float x[DIM];
  post_math(Cred, n, x);
  float y2 = 0.f;
#pragma unroll
  for (int i = 0; i < DIM; i++) y2 += x[i] * x[i];
  for (int c = 0; c < NCLS; c++) {
    float b2 = b2_s[c];
    float bx = 0.f;
    for (int d = 0; d < DIM; d++) bx += Bc[c * DIM + d] * x[d];
    float xy = -bx;
    float f1 = 1.0f + 2.0f * xy + y2;
    float f2 = 1.0f - b2;
    float den = fmaxf(1.0f + 2.0f * xy + b2 * y2, 1e-15f);
    float invden = 1.0f / den;
    float zn2 = 0.f, za = 0.f;
    for (int d = 0; d < DIM; d++) {
      float z = (f1 * (-Bc[c * DIM + d]) + f2 * x[d]) * invden;
      zn2 += z * z;
      za += z * Wc[d * NCLS + c];
    }
    float zn = fmaxf(sqrtf(fmaxf(zn2, 1e-30f)), 1e-10f);
    float dist = asinhf(2.0f * za / ((1.0f - zn * zn) * an_s[c]));
    LT[l_tile_idx(c, n)] = f2bf(lam_s[c] * an_s[c] * dist);
  }
}

// ---------------- MFMA matmul over fragment-linear tiles ----------------
// Every A-frag and B-frag load is ONE dense 1KB wave load (zero scatter).
template <int NF>
__global__ __launch_bounds__(256) void k_mm(const unsigned short* __restrict__ A,
                                            const unsigned short* __restrict__ BT,
                                            float* __restrict__ Cpart) {
  const int lane = threadIdx.x & 63;
  const int wid = threadIdx.x >> 6;
  const int r0 = blockIdx.x * 128 + wid * 32;
  const int kt0 = blockIdx.y * (KSEG / 32);  // global k-tile base
  const int lr = lane & 15;
  const int lkg = lane >> 4;
  const int poff = lr * 32 + lkg * 8;  // per-lane elem offset inside a tile
  const int BS = (NF == 3) ? 3 : 1;    // B tiles per k-tile
  f32x4 acc[2][NF];
#pragma unroll
  for (int m = 0; m < 2; m++)
#pragma unroll
    for (int nf = 0; nf < NF; nf++) acc[m][nf] = (f32x4){0.f, 0.f, 0.f, 0.f};
  const unsigned short* pa0 = A + ((size_t)(r0 >> 4) * NKT + kt0) * 512 + poff;
  const unsigned short* pa1 = pa0 + RT_STRIDE;
  const unsigned short* pbB = BT + (size_t)kt0 * BS * 512 + poff;
#pragma unroll 4
  for (int kt = 0; kt < KSEG / 32; kt++) {
    bf16x8 a0 = *(const bf16x8*)(pa0 + (size_t)kt * 512);
    bf16x8 a1 = *(const bf16x8*)(pa1 + (size_t)kt * 512);
#pragma unroll
    for (int nf = 0; nf < NF; nf++) {
      bf16x8 b = *(const bf16x8*)(pbB + (size_t)(kt * BS + nf) * 512);
      acc[0][nf] = __builtin_amdgcn_mfma_f32_16x16x32_bf16(a0, b, acc[0][nf], 0, 0, 0);
      acc[1][nf] = __builtin_amdgcn_mfma_f32_16x16x32_bf16(a1, b, acc[1][nf], 0, 0, 0);
    }
  }
  const int NCOL = (NF == 3) ? NCOLC : NF * 16;
  float* Cb = Cpart + (size_t)blockIdx.y * N_NODES * NCOL;
#pragma unroll
  for (int m = 0; m < 2; m++)
#pragma unroll
    for (int nf = 0; nf < NF; nf++) {
      if (NF == 3 && nf == 2 && lr >= 4) continue;  // cols 36..47 never read
#pragma unroll
      for (int j = 0; j < 4; j++) {
        int row = r0 + m * 16 + lkg * 4 + j;
        int col = nf * 16 + lr;
        Cb[(size_t)row * NCOL + col] = acc[m][nf][j];
      }
    }
}

// ---------------- splitK reduce (contiguous) ----------------
template <int TOTAL>
__global__ void k_red(const float* __restrict__ part, float* __restrict__ outb) {
  int i = blockIdx.x * blockDim.x + threadIdx.x;
  if (i < TOTAL) {
    float s = 0.f;
#pragma unroll
    for (int q = 0; q < SPLITK; q++) s += part[(size_t)q * TOTAL + i];
    outb[i] = s;
  }
}

extern "C" void kernel_launch(void* const* d_in, const int* in_sizes, int n_in,
                              void* d_out, int out_size, void* d_ws, size_t ws_size,
                              hipStream_t stream) {
  (void)in_sizes; (void)n_in; (void)out_size; (void)ws_size;
  const float* X  = (const float*)d_in[0];
  const float* A  = (const float*)d_in[1];
  const float* W1 = (const float*)d_in[2];
  const float* W2 = (const float*)d_in[3];
  const float* WL = (const float*)d_in[4];
  const float* PK = (const float*)d_in[5];
  float* out = (float*)d_out;

  char* ws = (char*)d_ws;
  unsigned short* Abf = (unsigned short*)ws;                  // 134,217,728 B (tiled)
  unsigned short* GT  = (unsigned short*)(ws + 134217728);    //     786,432 B (tiled)
  float* Cpart        = (float*)(ws + 135004160);             //  18,874,368 B
  float* Cred         = (float*)(ws + 153878528);             //   1,179,648 B
  unsigned short* LT  = (unsigned short*)(ws + 155058176);    //     262,144 B (tiled)

  // streaming LDS-transposing convert: dense on BOTH global sides
  k_convert<<<2048, 256, 0, stream>>>(A, Abf);

  // layer 1
  k_pre1<<<N_NODES / 64, 64, 0, stream>>>(X, W1, GT);
  k_mm<3><<<dim3(64, SPLITK), 256, 0, stream>>>(Abf, GT, Cpart);
  k_red<N_NODES * NCOLC><<<N_NODES * NCOLC / 256, 256, 0, stream>>>(Cpart, Cred);
  k_postpre<<<N_NODES / 64, 64, 0, stream>>>(Cred, W2, GT);

  // layer 2
  k_mm<3><<<dim3(64, SPLITK), 256, 0, stream>>>(Abf, GT, Cpart);
  k_red<N_NODES * NCOLC><<<N_NODES * NCOLC / 256, 256, 0, stream>>>(Cpart, Cred);
  k_postlogits<<<N_NODES / 64, 64, 0, stream>>>(Cred, WL, PK, LT);

  // logits aggregation
  k_mm<1><<<dim3(64, SPLITK), 256, 0, stream>>>(Abf, LT, Cpart);
  k_red<N_NODES * NCLS><<<N_NODES * NCLS / 256, 256, 0, stream>>>(Cpart, out);
}

// Round 10
// 190.660 us; speedup vs baseline: 2.9079x; 1.1152x over previous
//
#include <hip/hip_runtime.h>

#define N_NODES 8192
#define DIM 32
#define NCLS 16
#define SPLITK 16
#define KSEG (N_NODES / SPLITK) /* 512 */
#define NCOLC 36                /* packed partial-C columns (cols 36..47 structurally zero) */
#define NKT (N_NODES / 32)      /* 256 k-tiles per row stripe */
#define RT_STRIDE ((size_t)NKT * 512) /* elems per row-tile stripe */
#define PITCH 520               /* LDS row pitch in bf16 elems (1040B, 16B-aligned) */

typedef __bf16 bf16x8 __attribute__((ext_vector_type(8)));
typedef float f32x4 __attribute__((ext_vector_type(4)));

__device__ inline unsigned short f2bf(float f) {
  unsigned u = __float_as_uint(f);
  u = u + 0x7FFFu + ((u >> 16) & 1u);  // RNE
  return (unsigned short)(u >> 16);
}

__device__ inline float artanh_pos(float x) {  // x >= 0, clipped like jnp reference
  x = fminf(x, 1.0f - 1e-7f);
  return 0.5f * logf((1.0f + x) / (1.0f - x));
}

// ---- fragment-linear tile indexing ----
// A: [rt][kt][16 rows][32 k]  (1KB tiles; frag load = dense wave load)
// G: [nt][3 colblk][16 col][32 n]
__device__ inline size_t g_tile_idx(int c, int n) {
  return ((size_t)(n >> 5) * 3 + (c >> 4)) * 512 + (size_t)((c & 15) * 32 + (n & 31));
}
// L: [nt][16 col][32 n]
__device__ inline size_t l_tile_idx(int c, int n) {
  return (size_t)(n >> 5) * 512 + (size_t)(c * 32 + (n & 31));
}

// ---------------- FUSED: A fp32 -> bf16 tiles + mm pass 1 ----------------
// One block = one supertile (16 rows x 512 k). ph1: dense fp32 reads -> LDS.
// ph2a: MFMA straight from LDS (mm1's A-read costs zero global traffic).
// ph2b: dense contiguous Abf store. ph3: deterministic cross-wave reduce -> Cpart.
__global__ __launch_bounds__(256) void k_mmc(const float* __restrict__ A,
                                             const unsigned short* __restrict__ GT,
                                             unsigned short* __restrict__ Abf,
                                             float* __restrict__ Cpart) {
  __shared__ __align__(16) unsigned char ldsraw[16 * PITCH * 2];  // 16,640 B
  unsigned short* lds_t = (unsigned short*)ldsraw;
  float* lds_r = (float*)ldsraw;  // reused after barrier (needs 12,288 B)
  const int t = threadIdx.x;
  const int st = blockIdx.x;
  const int rt = st >> 4;  // row-tile (16 rows)
  const int ks = st & 15;  // k-supertile (512 k) == split index
  const int lane = t & 63;
  const int w = t >> 6;
  const int lr = lane & 15;
  const int lkg = lane >> 4;

  // ph1: dense 1KB-per-instruction reads, convert, stage to LDS row-major
  const float* src = A + (size_t)(rt * 16) * N_NODES + ks * 512;
#pragma unroll
  for (int v = 0; v < 8; v++) {
    const int row = 2 * v + (t >> 7);
    const int k = (t & 127) * 4;
    float4 f = *(const float4*)(src + (size_t)row * N_NODES + k);
    uint2 o;
    o.x = f2bf(f.x) | ((unsigned)f2bf(f.y) << 16);
    o.y = f2bf(f.z) | ((unsigned)f2bf(f.w) << 16);
    *(uint2*)(lds_t + row * PITCH + k) = o;
  }
  __syncthreads();

  // ph2a: MFMA — wave w owns local k-tiles 4w..4w+3 (K=128), all 3 col-blocks
  f32x4 acc[3];
#pragma unroll
  for (int nf = 0; nf < 3; nf++) acc[nf] = (f32x4){0.f, 0.f, 0.f, 0.f};
  const int poff = lr * 32 + lkg * 8;
#pragma unroll
  for (int i = 0; i < 4; i++) {
    const int kt2 = 4 * w + i;
    bf16x8 a = *(const bf16x8*)(lds_t + lr * PITCH + kt2 * 32 + lkg * 8);
#pragma unroll
    for (int nf = 0; nf < 3; nf++) {
      bf16x8 b = *(const bf16x8*)(GT + ((size_t)(ks * 16 + kt2) * 3 + nf) * 512 + poff);
      acc[nf] = __builtin_amdgcn_mfma_f32_16x16x32_bf16(a, b, acc[nf], 0, 0, 0);
    }
  }

  // ph2b: dense contiguous 16KB Abf supertile store (fragment-linear layout)
  unsigned short* dst = Abf + (size_t)st * 8192;
#pragma unroll
  for (int u = 0; u < 4; u++) {
    const int p = u * 256 + t;       // 16B-chunk index
    const int kt = p >> 6;           // local tile 0..15
    const int q = p & 63;
    const int row = q >> 2;
    const int kl = (q & 3) * 8;
    bf16x8 val = *(const bf16x8*)(lds_t + row * PITCH + kt * 32 + kl);
    *(bf16x8*)(dst + (size_t)p * 8) = val;
  }
  __syncthreads();  // lds_t dead; safe to reuse as lds_r

  // ph3a: dump per-wave acc into lds_r[w][16 rows][48 cols]
#pragma unroll
  for (int nf = 0; nf < 3; nf++)
#pragma unroll
    for (int j = 0; j < 4; j++)
      lds_r[(w * 16 + lkg * 4 + j) * 48 + nf * 16 + lr] = acc[nf][j];
  __syncthreads();

  // ph3b: deterministic 4-wave reduce -> Cpart[ks][rt*16+row][36]
  for (int e = t; e < 16 * 36; e += 256) {
    const int row = e / 36;
    const int col = e % 36;
    float s = lds_r[row * 48 + col] + lds_r[768 + row * 48 + col] +
              lds_r[1536 + row * 48 + col] + lds_r[2304 + row * 48 + col];
    Cpart[((size_t)ks * N_NODES + rt * 16 + row) * NCOLC + col] = s;
  }
}

// ---------------- pre: mobius_matvec + gamma -> G tiles ----------------
__device__ inline void pre_math(const float* __restrict__ Wl, const float x[DIM],
                                unsigned short* __restrict__ GT, int n) {
  float xn2 = 0.f;
#pragma unroll
  for (int i = 0; i < DIM; i++) xn2 += x[i] * x[i];
  float xn = sqrtf(fmaxf(xn2, 1e-30f));
  float mx[DIM];
#pragma unroll
  for (int j = 0; j < DIM; j++) mx[j] = 0.f;
  for (int i = 0; i < DIM; i++) {
    float xi = x[i];
#pragma unroll
    for (int j = 0; j < DIM; j++) mx[j] = fmaf(xi, Wl[i * DIM + j], mx[j]);
  }
  float mxn2 = 0.f;
#pragma unroll
  for (int j = 0; j < DIM; j++) mxn2 += mx[j] * mx[j];
  float mxn = sqrtf(fmaxf(mxn2, 1e-30f));
  float t = tanhf(mxn / xn * artanh_pos(xn));
  float sc = t / mxn;
  float xw[DIM];
  float x2n = 0.f;
#pragma unroll
  for (int j = 0; j < DIM; j++) { xw[j] = sc * mx[j]; x2n += xw[j] * xw[j]; }
  float gamma = 2.0f / fmaxf(1.0f - x2n, 1e-15f);
#pragma unroll
  for (int c = 0; c < DIM; c++) GT[g_tile_idx(c, n)] = f2bf(gamma * xw[c]);
  GT[g_tile_idx(32, n)] = f2bf(gamma - 1.0f);
  GT[g_tile_idx(33, n)] = f2bf(1.0f);
#pragma unroll
  for (int c = DIM + 2; c < 48; c++) GT[g_tile_idx(c, n)] = 0;
}

__global__ void k_pre1(const float* __restrict__ X, const float* __restrict__ W,
                       unsigned short* __restrict__ GT) {
  __shared__ float Wl[DIM * DIM];
  for (int i = threadIdx.x; i < DIM * DIM; i += blockDim.x) Wl[i] = W[i];
  __syncthreads();
  const int n = blockIdx.x * blockDim.x + threadIdx.x;
  float x[DIM];
#pragma unroll
  for (int i = 0; i < DIM; i += 4) {
    float4 v = *(const float4*)(X + (size_t)n * DIM + i);
    x[i] = v.x; x[i + 1] = v.y; x[i + 2] = v.z; x[i + 3] = v.w;
  }
  pre_math(Wl, x, GT, n);
}

// ---------------- post math: reads reduced C [N][36] ----------------
__device__ inline void post_math(const float* __restrict__ Cred, int n, float xo[DIM]) {
  float acc[36];
  const float4* p = (const float4*)(Cred + (size_t)n * NCOLC);
#pragma unroll
  for (int q = 0; q < 9; q++) {
    float4 v = p[q];
    acc[q * 4 + 0] = v.x; acc[q * 4 + 1] = v.y;
    acc[q * 4 + 2] = v.z; acc[q * 4 + 3] = v.w;
  }
  float denom = acc[32];
  float alpha = acc[33];
  denom = (denom >= 0.f) ? fmaxf(denom, 1e-10f) : fminf(denom, -1e-10f);
  float inv = 1.0f / denom;
  float v[DIM];
  float vn2 = 0.f;
#pragma unroll
  for (int c = 0; c < DIM; c++) { v[c] = acc[c] * inv; vn2 += v[c] * v[c]; }
  float vn = sqrtf(fmaxf(vn2, 1e-30f));
  float un = alpha * 0.5f * artanh_pos(vn);
  float su = un / vn;
  float r[DIM];
  float rn2 = 0.f;
#pragma unroll
  for (int c = 0; c < DIM; c++) { r[c] = fmaxf(su * v[c], 0.f); rn2 += r[c] * r[c]; }
  float rn = sqrtf(fmaxf(rn2, 1e-30f));
  float so = tanhf(rn) / rn;
#pragma unroll
  for (int c = 0; c < DIM; c++) xo[c] = so * r[c];
}

__global__ void k_postpre(const float* __restrict__ Cred, const float* __restrict__ W,
                          unsigned short* __restrict__ GT) {
  __shared__ float Wl[DIM * DIM];
  for (int i = threadIdx.x; i < DIM * DIM; i += blockDim.x) Wl[i] = W[i];
  __syncthreads();
  const int n = blockIdx.x * blockDim.x + threadIdx.x;
  float x[DIM];
  post_math(Cred, n, x);
  pre_math(Wl, x, GT, n);
}

__global__ void k_postlogits(const float* __restrict__ Cred, const float* __restrict__ Wl_g,
                             const float* __restrict__ B_g, unsigned short* __restrict__ LT) {
  __shared__ float Wc[DIM * NCLS];
  __shared__ float Bc[NCLS * DIM];
  __shared__ float an_s[NCLS], lam_s[NCLS], b2_s[NCLS];
  for (int i = threadIdx.x; i < DIM * NCLS; i += blockDim.x) { Wc[i] = Wl_g[i]; Bc[i] = B_g[i]; }
  __syncthreads();
  if (threadIdx.x < NCLS) {
    int c = threadIdx.x;
    float b2 = 0.f, w2 = 0.f;
    for (int d = 0; d < DIM; d++) {
      b2 += Bc[c * DIM + d] * Bc[c * DIM + d];
      w2 += Wc[d * NCLS + c] * Wc[d * NCLS + c];
    }
    b2_s[c] = b2;
    an_s[c] = fmaxf(sqrtf(w2), 1e-10f);
    lam_s[c] = 2.0f / fmaxf(1.0f - b2, 1e-15f);
  }
  __syncthreads();
  const int n = blockIdx.x * blockDim.x + threadIdx.x;
  float x[DIM];
  post_math(Cred, n, x);
  float y2 = 0.f;
#pragma unroll
  for (int i = 0; i < DIM; i++) y2 += x[i] * x[i];
  for (int c = 0; c < NCLS; c++) {
    float b2 = b2_s[c];
    float bx = 0.f;
    for (int d = 0; d < DIM; d++) bx += Bc[c * DIM + d] * x[d];
    float xy = -bx;
    float f1 = 1.0f + 2.0f * xy + y2;
    float f2 = 1.0f - b2;
    float den = fmaxf(1.0f + 2.0f * xy + b2 * y2, 1e-15f);
    float invden = 1.0f / den;
    float zn2 = 0.f, za = 0.f;
    for (int d = 0; d < DIM; d++) {
      float z = (f1 * (-Bc[c * DIM + d]) + f2 * x[d]) * invden;
      zn2 += z * z;
      za += z * Wc[d * NCLS + c];
    }
    float zn = fmaxf(sqrtf(fmaxf(zn2, 1e-30f)), 1e-10f);
    float dist = asinhf(2.0f * za / ((1.0f - zn * zn) * an_s[c]));
    LT[l_tile_idx(c, n)] = f2bf(lam_s[c] * an_s[c] * dist);
  }
}

// ---------------- MFMA matmul over fragment-linear tiles (passes 2/3) ----------------
template <int NF>
__global__ __launch_bounds__(256) void k_mm(const unsigned short* __restrict__ A,
                                            const unsigned short* __restrict__ BT,
                                            float* __restrict__ Cpart) {
  const int lane = threadIdx.x & 63;
  const int wid = threadIdx.x >> 6;
  const int r0 = blockIdx.x * 128 + wid * 32;
  const int kt0 = blockIdx.y * (KSEG / 32);
  const int lr = lane & 15;
  const int lkg = lane >> 4;
  const int poff = lr * 32 + lkg * 8;
  const int BS = (NF == 3) ? 3 : 1;
  f32x4 acc[2][NF];
#pragma unroll
  for (int m = 0; m < 2; m++)
#pragma unroll
    for (int nf = 0; nf < NF; nf++) acc[m][nf] = (f32x4){0.f, 0.f, 0.f, 0.f};
  const unsigned short* pa0 = A + ((size_t)(r0 >> 4) * NKT + kt0) * 512 + poff;
  const unsigned short* pa1 = pa0 + RT_STRIDE;
  const unsigned short* pbB = BT + (size_t)kt0 * BS * 512 + poff;
#pragma unroll 4
  for (int kt = 0; kt < KSEG / 32; kt++) {
    bf16x8 a0 = *(const bf16x8*)(pa0 + (size_t)kt * 512);
    bf16x8 a1 = *(const bf16x8*)(pa1 + (size_t)kt * 512);
#pragma unroll
    for (int nf = 0; nf < NF; nf++) {
      bf16x8 b = *(const bf16x8*)(pbB + (size_t)(kt * BS + nf) * 512);
      acc[0][nf] = __builtin_amdgcn_mfma_f32_16x16x32_bf16(a0, b, acc[0][nf], 0, 0, 0);
      acc[1][nf] = __builtin_amdgcn_mfma_f32_16x16x32_bf16(a1, b, acc[1][nf], 0, 0, 0);
    }
  }
  const int NCOL = (NF == 3) ? NCOLC : NF * 16;
  float* Cb = Cpart + (size_t)blockIdx.y * N_NODES * NCOL;
#pragma unroll
  for (int m = 0; m < 2; m++)
#pragma unroll
    for (int nf = 0; nf < NF; nf++) {
      if (NF == 3 && nf == 2 && lr >= 4) continue;
#pragma unroll
      for (int j = 0; j < 4; j++) {
        int row = r0 + m * 16 + lkg * 4 + j;
        int col = nf * 16 + lr;
        Cb[(size_t)row * NCOL + col] = acc[m][nf][j];
      }
    }
}

// ---------------- splitK reduce (contiguous) ----------------
template <int TOTAL>
__global__ void k_red(const float* __restrict__ part, float* __restrict__ outb) {
  int i = blockIdx.x * blockDim.x + threadIdx.x;
  if (i < TOTAL) {
    float s = 0.f;
#pragma unroll
    for (int q = 0; q < SPLITK; q++) s += part[(size_t)q * TOTAL + i];
    outb[i] = s;
  }
}

extern "C" void kernel_launch(void* const* d_in, const int* in_sizes, int n_in,
                              void* d_out, int out_size, void* d_ws, size_t ws_size,
                              hipStream_t stream) {
  (void)in_sizes; (void)n_in; (void)out_size; (void)ws_size;
  const float* X  = (const float*)d_in[0];
  const float* A  = (const float*)d_in[1];
  const float* W1 = (const float*)d_in[2];
  const float* W2 = (const float*)d_in[3];
  const float* WL = (const float*)d_in[4];
  const float* PK = (const float*)d_in[5];
  float* out = (float*)d_out;

  char* ws = (char*)d_ws;
  unsigned short* Abf = (unsigned short*)ws;                  // 134,217,728 B (tiled)
  unsigned short* GT  = (unsigned short*)(ws + 134217728);    //     786,432 B (tiled)
  float* Cpart        = (float*)(ws + 135004160);             //  18,874,368 B
  float* Cred         = (float*)(ws + 153878528);             //   1,179,648 B
  unsigned short* LT  = (unsigned short*)(ws + 155058176);    //     262,144 B (tiled)

  // layer 1: fused convert + mm1 (the only toucher of HBM-cold A)
  k_pre1<<<N_NODES / 64, 64, 0, stream>>>(X, W1, GT);
  k_mmc<<<8192, 256, 0, stream>>>(A, GT, Abf, Cpart);
  k_red<N_NODES * NCOLC><<<N_NODES * NCOLC / 256, 256, 0, stream>>>(Cpart, Cred);
  k_postpre<<<N_NODES / 64, 64, 0, stream>>>(Cred, W2, GT);

  // layer 2
  k_mm<3><<<dim3(64, SPLITK), 256, 0, stream>>>(Abf, GT, Cpart);
  k_red<N_NODES * NCOLC><<<N_NODES * NCOLC / 256, 256, 0, stream>>>(Cpart, Cred);
  k_postlogits<<<N_NODES / 64, 64, 0, stream>>>(Cred, WL, PK, LT);

  // logits aggregation
  k_mm<1><<<dim3(64, SPLITK), 256, 0, stream>>>(Abf, LT, Cpart);
  k_red<N_NODES * NCLS><<<N_NODES * NCLS / 256, 256, 0, stream>>>(Cpart, out);
}

// Round 11
// 181.975 us; speedup vs baseline: 3.0466x; 1.0477x over previous
//
#include <hip/hip_runtime.h>

#define N_NODES 8192
#define DIM 32
#define NCLS 16
#define SPLITK 16
#define KSEG (N_NODES / SPLITK) /* 512 */
#define NCOLC 36                /* packed partial-C columns (cols 36..47 structurally zero) */
#define NKT (N_NODES / 32)      /* 256 k-tiles per row stripe */
#define RT_STRIDE ((size_t)NKT * 512) /* elems per row-tile stripe */
#define PITCH 520               /* LDS row pitch in bf16 elems (1040B, 16B-aligned) */

typedef __bf16 bf16x8 __attribute__((ext_vector_type(8)));
typedef float f32x4 __attribute__((ext_vector_type(4)));

__device__ inline unsigned short f2bf(float f) {
  unsigned u = __float_as_uint(f);
  u = u + 0x7FFFu + ((u >> 16) & 1u);  // RNE
  return (unsigned short)(u >> 16);
}

__device__ inline float artanh_pos(float x) {  // x >= 0, clipped like jnp reference
  x = fminf(x, 1.0f - 1e-7f);
  return 0.5f * logf((1.0f + x) / (1.0f - x));
}

// ---- fragment-linear tile indexing ----
// A: [rt][kt][16 rows][32 k]  (1KB tiles; frag load = dense wave load)
// G: [nt][3 colblk][16 col][32 n]
__device__ inline size_t g_tile_idx(int c, int n) {
  return ((size_t)(n >> 5) * 3 + (c >> 4)) * 512 + (size_t)((c & 15) * 32 + (n & 31));
}
// L: [nt][16 col][32 n]
__device__ inline size_t l_tile_idx(int c, int n) {
  return (size_t)(n >> 5) * 512 + (size_t)(c * 32 + (n & 31));
}

// ---------------- FUSED: A fp32 -> bf16 tiles + mm pass 1 ----------------
// ph1: NON-TEMPORAL dense fp32 reads -> LDS (A has zero reuse; keep L3 for Abf).
// ph2a: MFMA straight from LDS. ph2b: dense contiguous Abf store (cached -> L3-resident
// for mm2). ph3: deterministic cross-wave reduce -> Cpart.
__global__ __launch_bounds__(256) void k_mmc(const float* __restrict__ A,
                                             const unsigned short* __restrict__ GT,
                                             unsigned short* __restrict__ Abf,
                                             float* __restrict__ Cpart) {
  __shared__ __align__(16) unsigned char ldsraw[16 * PITCH * 2];  // 16,640 B
  unsigned short* lds_t = (unsigned short*)ldsraw;
  float* lds_r = (float*)ldsraw;  // reused after barrier (needs 12,288 B)
  const int t = threadIdx.x;
  const int st = blockIdx.x;
  const int rt = st >> 4;  // row-tile (16 rows)
  const int ks = st & 15;  // k-supertile (512 k) == split index
  const int lane = t & 63;
  const int w = t >> 6;
  const int lr = lane & 15;
  const int lkg = lane >> 4;

  // ph1: dense 1KB-per-instruction NT reads, convert, stage to LDS row-major
  const float* src = A + (size_t)(rt * 16) * N_NODES + ks * 512;
#pragma unroll
  for (int v = 0; v < 8; v++) {
    const int row = 2 * v + (t >> 7);
    const int k = (t & 127) * 4;
    f32x4 f = __builtin_nontemporal_load((const f32x4*)(src + (size_t)row * N_NODES + k));
    uint2 o;
    o.x = f2bf(f[0]) | ((unsigned)f2bf(f[1]) << 16);
    o.y = f2bf(f[2]) | ((unsigned)f2bf(f[3]) << 16);
    *(uint2*)(lds_t + row * PITCH + k) = o;
  }
  __syncthreads();

  // ph2a: MFMA — wave w owns local k-tiles 4w..4w+3 (K=128), all 3 col-blocks
  f32x4 acc[3];
#pragma unroll
  for (int nf = 0; nf < 3; nf++) acc[nf] = (f32x4){0.f, 0.f, 0.f, 0.f};
  const int poff = lr * 32 + lkg * 8;
#pragma unroll
  for (int i = 0; i < 4; i++) {
    const int kt2 = 4 * w + i;
    bf16x8 a = *(const bf16x8*)(lds_t + lr * PITCH + kt2 * 32 + lkg * 8);
#pragma unroll
    for (int nf = 0; nf < 3; nf++) {
      bf16x8 b = *(const bf16x8*)(GT + ((size_t)(ks * 16 + kt2) * 3 + nf) * 512 + poff);
      acc[nf] = __builtin_amdgcn_mfma_f32_16x16x32_bf16(a, b, acc[nf], 0, 0, 0);
    }
  }

  // ph2b: dense contiguous 16KB Abf supertile store (fragment-linear layout)
  unsigned short* dst = Abf + (size_t)st * 8192;
#pragma unroll
  for (int u = 0; u < 4; u++) {
    const int p = u * 256 + t;       // 16B-chunk index
    const int kt = p >> 6;           // local tile 0..15
    const int q = p & 63;
    const int row = q >> 2;
    const int kl = (q & 3) * 8;
    bf16x8 val = *(const bf16x8*)(lds_t + row * PITCH + kt * 32 + kl);
    *(bf16x8*)(dst + (size_t)p * 8) = val;
  }
  __syncthreads();  // lds_t dead; safe to reuse as lds_r

  // ph3a: dump per-wave acc into lds_r[w][16 rows][48 cols]
#pragma unroll
  for (int nf = 0; nf < 3; nf++)
#pragma unroll
    for (int j = 0; j < 4; j++)
      lds_r[(w * 16 + lkg * 4 + j) * 48 + nf * 16 + lr] = acc[nf][j];
  __syncthreads();

  // ph3b: deterministic 4-wave reduce -> Cpart[ks][rt*16+row][36]
  for (int e = t; e < 16 * 36; e += 256) {
    const int row = e / 36;
    const int col = e % 36;
    float s = lds_r[row * 48 + col] + lds_r[768 + row * 48 + col] +
              lds_r[1536 + row * 48 + col] + lds_r[2304 + row * 48 + col];
    Cpart[((size_t)ks * N_NODES + rt * 16 + row) * NCOLC + col] = s;
  }
}

// ---------------- pre: mobius_matvec + gamma -> G tiles ----------------
__device__ inline void pre_math(const float* __restrict__ Wl, const float x[DIM],
                                unsigned short* __restrict__ GT, int n) {
  float xn2 = 0.f;
#pragma unroll
  for (int i = 0; i < DIM; i++) xn2 += x[i] * x[i];
  float xn = sqrtf(fmaxf(xn2, 1e-30f));
  float mx[DIM];
#pragma unroll
  for (int j = 0; j < DIM; j++) mx[j] = 0.f;
  for (int i = 0; i < DIM; i++) {
    float xi = x[i];
#pragma unroll
    for (int j = 0; j < DIM; j++) mx[j] = fmaf(xi, Wl[i * DIM + j], mx[j]);
  }
  float mxn2 = 0.f;
#pragma unroll
  for (int j = 0; j < DIM; j++) mxn2 += mx[j] * mx[j];
  float mxn = sqrtf(fmaxf(mxn2, 1e-30f));
  float t = tanhf(mxn / xn * artanh_pos(xn));
  float sc = t / mxn;
  float xw[DIM];
  float x2n = 0.f;
#pragma unroll
  for (int j = 0; j < DIM; j++) { xw[j] = sc * mx[j]; x2n += xw[j] * xw[j]; }
  float gamma = 2.0f / fmaxf(1.0f - x2n, 1e-15f);
#pragma unroll
  for (int c = 0; c < DIM; c++) GT[g_tile_idx(c, n)] = f2bf(gamma * xw[c]);
  GT[g_tile_idx(32, n)] = f2bf(gamma - 1.0f);
  GT[g_tile_idx(33, n)] = f2bf(1.0f);
#pragma unroll
  for (int c = DIM + 2; c < 48; c++) GT[g_tile_idx(c, n)] = 0;
}

__global__ void k_pre1(const float* __restrict__ X, const float* __restrict__ W,
                       unsigned short* __restrict__ GT) {
  __shared__ float Wl[DIM * DIM];
  for (int i = threadIdx.x; i < DIM * DIM; i += blockDim.x) Wl[i] = W[i];
  __syncthreads();
  const int n = blockIdx.x * blockDim.x + threadIdx.x;
  float x[DIM];
#pragma unroll
  for (int i = 0; i < DIM; i += 4) {
    float4 v = *(const float4*)(X + (size_t)n * DIM + i);
    x[i] = v.x; x[i + 1] = v.y; x[i + 2] = v.z; x[i + 3] = v.w;
  }
  pre_math(Wl, x, GT, n);
}

// ---------------- post math: reduces Cpart's 16 splits directly (same s-order as k_red) ----------------
__device__ inline void post_math(const float* __restrict__ Cpart, int n, float xo[DIM]) {
  float acc[NCOLC];
#pragma unroll
  for (int c = 0; c < NCOLC; c++) acc[c] = 0.f;
  for (int s = 0; s < SPLITK; s++) {
    const float4* p = (const float4*)(Cpart + ((size_t)s * N_NODES + n) * NCOLC);
#pragma unroll
    for (int q = 0; q < NCOLC / 4; q++) {
      float4 v = p[q];
      acc[q * 4 + 0] += v.x; acc[q * 4 + 1] += v.y;
      acc[q * 4 + 2] += v.z; acc[q * 4 + 3] += v.w;
    }
  }
  float denom = acc[32];
  float alpha = acc[33];
  denom = (denom >= 0.f) ? fmaxf(denom, 1e-10f) : fminf(denom, -1e-10f);
  float inv = 1.0f / denom;
  float v[DIM];
  float vn2 = 0.f;
#pragma unroll
  for (int c = 0; c < DIM; c++) { v[c] = acc[c] * inv; vn2 += v[c] * v[c]; }
  float vn = sqrtf(fmaxf(vn2, 1e-30f));
  float un = alpha * 0.5f * artanh_pos(vn);
  float su = un / vn;
  float r[DIM];
  float rn2 = 0.f;
#pragma unroll
  for (int c = 0; c < DIM; c++) { r[c] = fmaxf(su * v[c], 0.f); rn2 += r[c] * r[c]; }
  float rn = sqrtf(fmaxf(rn2, 1e-30f));
  float so = tanhf(rn) / rn;
#pragma unroll
  for (int c = 0; c < DIM; c++) xo[c] = so * r[c];
}

__global__ void k_postpre(const float* __restrict__ Cpart, const float* __restrict__ W,
                          unsigned short* __restrict__ GT) {
  __shared__ float Wl[DIM * DIM];
  for (int i = threadIdx.x; i < DIM * DIM; i += blockDim.x) Wl[i] = W[i];
  __syncthreads();
  const int n = blockIdx.x * blockDim.x + threadIdx.x;
  float x[DIM];
  post_math(Cpart, n, x);
  pre_math(Wl, x, GT, n);
}

__global__ void k_postlogits(const float* __restrict__ Cpart, const float* __restrict__ Wl_g,
                             const float* __restrict__ B_g, unsigned short* __restrict__ LT) {
  __shared__ float Wc[DIM * NCLS];
  __shared__ float Bc[NCLS * DIM];
  __shared__ float an_s[NCLS], lam_s[NCLS], b2_s[NCLS];
  for (int i = threadIdx.x; i < DIM * NCLS; i += blockDim.x) { Wc[i] = Wl_g[i]; Bc[i] = B_g[i]; }
  __syncthreads();
  if (threadIdx.x < NCLS) {
    int c = threadIdx.x;
    float b2 = 0.f, w2 = 0.f;
    for (int d = 0; d < DIM; d++) {
      b2 += Bc[c * DIM + d] * Bc[c * DIM + d];
      w2 += Wc[d * NCLS + c] * Wc[d * NCLS + c];
    }
    b2_s[c] = b2;
    an_s[c] = fmaxf(sqrtf(w2), 1e-10f);
    lam_s[c] = 2.0f / fmaxf(1.0f - b2, 1e-15f);
  }
  __syncthreads();
  const int n = blockIdx.x * blockDim.x + threadIdx.x;
  float x[DIM];
  post_math(Cpart, n, x);
  float y2 = 0.f;
#pragma unroll
  for (int i = 0; i < DIM; i++) y2 += x[i] * x[i];
  for (int c = 0; c < NCLS; c++) {
    float b2 = b2_s[c];
    float bx = 0.f;
    for (int d = 0; d < DIM; d++) bx += Bc[c * DIM + d] * x[d];
    float xy = -bx;
    float f1 = 1.0f + 2.0f * xy + y2;
    float f2 = 1.0f - b2;
    float den = fmaxf(1.0f + 2.0f * xy + b2 * y2, 1e-15f);
    float invden = 1.0f / den;
    float zn2 = 0.f, za = 0.f;
    for (int d = 0; d < DIM; d++) {
      float z = (f1 * (-Bc[c * DIM + d]) + f2 * x[d]) * invden;
      zn2 += z * z;
      za += z * Wc[d * NCLS + c];
    }
    float zn = fmaxf(sqrtf(fmaxf(zn2, 1e-30f)), 1e-10f);
    float dist = asinhf(2.0f * za / ((1.0f - zn * zn) * an_s[c]));
    LT[l_tile_idx(c, n)] = f2bf(lam_s[c] * an_s[c] * dist);
  }
}

// ---------------- MFMA matmul over fragment-linear tiles (passes 2/3) ----------------
template <int NF>
__global__ __launch_bounds__(256) void k_mm(const unsigned short* __restrict__ A,
                                            const unsigned short* __restrict__ BT,
                                            float* __restrict__ Cpart) {
  const int lane = threadIdx.x & 63;
  const int wid = threadIdx.x >> 6;
  const int r0 = blockIdx.x * 128 + wid * 32;
  const int kt0 = blockIdx.y * (KSEG / 32);
  const int lr = lane & 15;
  const int lkg = lane >> 4;
  const int poff = lr * 32 + lkg * 8;
  const int BS = (NF == 3) ? 3 : 1;
  f32x4 acc[2][NF];
#pragma unroll
  for (int m = 0; m < 2; m++)
#pragma unroll
    for (int nf = 0; nf < NF; nf++) acc[m][nf] = (f32x4){0.f, 0.f, 0.f, 0.f};
  const unsigned short* pa0 = A + ((size_t)(r0 >> 4) * NKT + kt0) * 512 + poff;
  const unsigned short* pa1 = pa0 + RT_STRIDE;
  const unsigned short* pbB = BT + (size_t)kt0 * BS * 512 + poff;
#pragma unroll 4
  for (int kt = 0; kt < KSEG / 32; kt++) {
    bf16x8 a0 = *(const bf16x8*)(pa0 + (size_t)kt * 512);
    bf16x8 a1 = *(const bf16x8*)(pa1 + (size_t)kt * 512);
#pragma unroll
    for (int nf = 0; nf < NF; nf++) {
      bf16x8 b = *(const bf16x8*)(pbB + (size_t)(kt * BS + nf) * 512);
      acc[0][nf] = __builtin_amdgcn_mfma_f32_16x16x32_bf16(a0, b, acc[0][nf], 0, 0, 0);
      acc[1][nf] = __builtin_amdgcn_mfma_f32_16x16x32_bf16(a1, b, acc[1][nf], 0, 0, 0);
    }
  }
  const int NCOL = (NF == 3) ? NCOLC : NF * 16;
  float* Cb = Cpart + (size_t)blockIdx.y * N_NODES * NCOL;
#pragma unroll
  for (int m = 0; m < 2; m++)
#pragma unroll
    for (int nf = 0; nf < NF; nf++) {
      if (NF == 3 && nf == 2 && lr >= 4) continue;
#pragma unroll
      for (int j = 0; j < 4; j++) {
        int row = r0 + m * 16 + lkg * 4 + j;
        int col = nf * 16 + lr;
        Cb[(size_t)row * NCOL + col] = acc[m][nf][j];
      }
    }
}

// ---------------- splitK reduce for the final output ----------------
template <int TOTAL>
__global__ void k_red(const float* __restrict__ part, float* __restrict__ outb) {
  int i = blockIdx.x * blockDim.x + threadIdx.x;
  if (i < TOTAL) {
    float s = 0.f;
#pragma unroll
    for (int q = 0; q < SPLITK; q++) s += part[(size_t)q * TOTAL + i];
    outb[i] = s;
  }
}

extern "C" void kernel_launch(void* const* d_in, const int* in_sizes, int n_in,
                              void* d_out, int out_size, void* d_ws, size_t ws_size,
                              hipStream_t stream) {
  (void)in_sizes; (void)n_in; (void)out_size; (void)ws_size;
  const float* X  = (const float*)d_in[0];
  const float* A  = (const float*)d_in[1];
  const float* W1 = (const float*)d_in[2];
  const float* W2 = (const float*)d_in[3];
  const float* WL = (const float*)d_in[4];
  const float* PK = (const float*)d_in[5];
  float* out = (float*)d_out;

  char* ws = (char*)d_ws;
  unsigned short* Abf = (unsigned short*)ws;                  // 134,217,728 B (tiled)
  unsigned short* GT  = (unsigned short*)(ws + 134217728);    //     786,432 B (tiled)
  float* Cpart        = (float*)(ws + 135004160);             //  18,874,368 B
  unsigned short* LT  = (unsigned short*)(ws + 153878528);    //     262,144 B (tiled)

  // layer 1: fused convert + mm1 (nt-reads A; Abf write stays L3-resident)
  k_pre1<<<N_NODES / 64, 64, 0, stream>>>(X, W1, GT);
  k_mmc<<<8192, 256, 0, stream>>>(A, GT, Abf, Cpart);
  k_postpre<<<N_NODES / 64, 64, 0, stream>>>(Cpart, W2, GT);

  // layer 2
  k_mm<3><<<dim3(64, SPLITK), 256, 0, stream>>>(Abf, GT, Cpart);
  k_postlogits<<<N_NODES / 64, 64, 0, stream>>>(Cpart, WL, PK, LT);

  // logits aggregation
  k_mm<1><<<dim3(64, SPLITK), 256, 0, stream>>>(Abf, LT, Cpart);
  k_red<N_NODES * NCLS><<<N_NODES * NCLS / 256, 256, 0, stream>>>(Cpart, out);
}